// Round 5
// baseline (788.981 us; speedup 1.0000x reference)
//
#include <hip/hip_runtime.h>
#include <stdint.h>

#define T_STEPS 512
#define F_IN 30
#define HID 32
#define LOG2E 1.44269504088896340736f

typedef __attribute__((ext_vector_type(8))) short short8;   // 8 bf16 (4 VGPRs)
typedef __attribute__((ext_vector_type(4))) float floatx4;  // 4 f32 acc

#define MFMA(a, b, c) __builtin_amdgcn_mfma_f32_16x16x32_bf16((a), (b), (c), 0, 0, 0)

__device__ __forceinline__ unsigned short f2bf(float f) {
    uint32_t u = __float_as_uint(f);
    u += 0x7fffu + ((u >> 16) & 1u);            // RTNE
    return (unsigned short)(u >> 16);
}
__device__ __forceinline__ float bf2f(unsigned short h) {
    return __uint_as_float(((uint32_t)h) << 16);
}
// packed f32->bf16 RTNE, single VALU op (gfx950); lo16 = S0, hi16 = S1
__device__ __forceinline__ uint32_t cvtpk(float a, float b) {
    uint32_t r;
    asm("v_cvt_pk_bf16_f32 %0, %1, %2" : "=v"(r) : "v"(a), "v"(b));
    return r;
}
__device__ __forceinline__ float rcp_f(float x) { return __builtin_amdgcn_rcpf(x); }
#if __has_builtin(__builtin_amdgcn_exp2f)
__device__ __forceinline__ float exp2_f(float x) { return __builtin_amdgcn_exp2f(x); }
#else
__device__ __forceinline__ float exp2_f(float x) { return exp2f(x); }
#endif

__device__ __forceinline__ void loadx8(float (&d)[8], const float* p, bool tail) {
    float2 a0 = *(const float2*)(p + 0);
    float2 a1 = *(const float2*)(p + 2);
    float2 a2 = *(const float2*)(p + 4);
    float2 a3 = make_float2(0.f, 0.f);
    if (!tail) a3 = *(const float2*)(p + 6);     // quad3: feats 24..29 only; slots 6,7 set at cvt
    d[0]=a0.x; d[1]=a0.y; d[2]=a1.x; d[3]=a1.y;
    d[4]=a2.x; d[5]=a2.y; d[6]=a3.x; d[7]=a3.y;
}

// One wave = one block = 16 batch rows, fully self-contained LSTM chain.
// Zero LDS / barriers / cross-lane traffic (unit permutation P makes h lane-local).
// This revision: explicit 1-step software pipeline —
//   accx(t+1) (x-only MFMAs) computed during step t, h-MFMAs seed from accx_p (C-in),
//   head(t-1) issued as filler during step t's front. Recurrent path per step:
//   3 MFMAs -> act -> update -> pack.
__global__ __launch_bounds__(64, 1)
void lstm_wave_kernel(const float* __restrict__ x, const float* __restrict__ h0,
                      const float* __restrict__ c0, const float* __restrict__ W_ih,
                      const float* __restrict__ W_hh, const float* __restrict__ b_ih,
                      const float* __restrict__ b_hh, const float* __restrict__ W_all,
                      const float* __restrict__ b_all, const float* __restrict__ W_pos,
                      const float* __restrict__ b_pos, const float* __restrict__ W_lv,
                      const float* __restrict__ b_lv, float* __restrict__ pos_out,
                      float* __restrict__ lv_out, float* __restrict__ hT_out,
                      float* __restrict__ cT_out)
{
    const int lane = threadIdx.x;     // block = 64 threads = 1 wave
    const int quad = lane >> 4;
    const int l15  = lane & 15;
    const int row  = blockIdx.x * 16 + l15;   // this lane's batch row (B-frag n, update row)

    // ---- gate weight A-frags: 8 M-tiles of 16 gate-rows, hi/lo split, exp2-folded ----
    // k slots 30/31 of the x-weights carry the bias (x slots 30/31 are set to 1.0).
    short8 wxh[8], wxl[8], whh[8], whl[8];
#pragma unroll
    for (int mt = 0; mt < 8; ++mt) {
        const float gs = ((mt == 4) || (mt == 5) ? -2.0f : -1.0f) * LOG2E;
        const int m = mt * 16 + l15;
        const int c = m & 31;
        const int u = 8 * ((c & 15) >> 2) + 4 * (c >> 4) + (c & 3);   // P(c)
        const int R = (m >> 5) * 32 + u;                              // original weight row
        const float bias = (b_ih[R] + b_hh[R]) * gs;
#pragma unroll
        for (int j = 0; j < 8; ++j) {
            const int k = quad * 8 + j;
            float wx = (k < F_IN) ? W_ih[R * F_IN + k] * gs : (k == F_IN ? bias : 0.0f);
            unsigned short hx = f2bf(wx);
            wxh[mt][j] = (short)hx; wxl[mt][j] = (short)f2bf(wx - bf2f(hx));
            float wh = W_hh[R * HID + k] * gs;
            unsigned short hh = f2bf(wh);
            whh[mt][j] = (short)hh; whl[mt][j] = (short)f2bf(wh - bf2f(hh));
        }
    }

    // ---- head A-frags: m-row 0 = pos0, 1 = pos1, 2 = leave, 3..15 = zero ----
    short8 wph, wpl;
#pragma unroll
    for (int j = 0; j < 8; ++j) {
        const int k = quad * 8 + j;   // physical hidden unit
        float w = 0.0f;
        if (l15 == 0)      { for (int o = 0; o < HID; ++o) w += W_pos[o]       * W_all[o * HID + k]; }
        else if (l15 == 1) { for (int o = 0; o < HID; ++o) w += W_pos[HID + o] * W_all[o * HID + k]; }
        else if (l15 == 2) { w = W_lv[k]; }
        unsigned short hw_ = f2bf(w);
        wph[j] = (short)hw_; wpl[j] = (short)f2bf(w - bf2f(hw_));
    }
    float bc0 = b_pos[0], bc1 = b_pos[1];
    for (int o = 0; o < HID; ++o) { bc0 += W_pos[o] * b_all[o]; bc1 += W_pos[HID + o] * b_all[o]; }
    const float blv = b_lv[0];

    // ---- state: lane owns (row, units 8*quad .. 8*quad+7) ----
    union HU { uint32_t u[4]; short8 s; };
    float cst[8];
    HU Hh, Hl;                                  // h as bf16 hi/lo pairs == next-step B-frag words
    {
        const float* hp = h0 + (size_t)row * HID + quad * 8;
        const float* cp = c0 + (size_t)row * HID + quad * 8;
        float hv[8];
#pragma unroll
        for (int j = 0; j < 8; ++j) { hv[j] = hp[j]; cst[j] = cp[j]; }
#pragma unroll
        for (int w = 0; w < 4; ++w) {
            const uint32_t ph = cvtpk(hv[2 * w], hv[2 * w + 1]);
            const float r0 = hv[2 * w]     - __uint_as_float(ph << 16);
            const float r1 = hv[2 * w + 1] - __uint_as_float(ph & 0xffff0000u);
            Hh.u[w] = ph; Hl.u[w] = cvtpk(r0, r1);
        }
    }

    // ---- x / mask prefetch ring (depth 4) ----
    const float* xlane = x + (size_t)row * T_STEPS * F_IN + quad * 8;
    const float* mptr  = x + (size_t)row * T_STEPS * F_IN + (F_IN - 1);
    const bool tail = (quad == 3);

    float xr0[8] = {0,0,0,0,0,0,0,0}, xr1[8] = {0,0,0,0,0,0,0,0};
    float xr2[8] = {0,0,0,0,0,0,0,0}, xr3[8] = {0,0,0,0,0,0,0,0};
    float mr0, mr1, mr2, mr3;
    loadx8(xr0, xlane + 0 * F_IN, tail);  mr0 = mptr[0 * F_IN];
    loadx8(xr1, xlane + 1 * F_IN, tail);  mr1 = mptr[1 * F_IN];
    loadx8(xr2, xlane + 2 * F_IN, tail);  mr2 = mptr[2 * F_IN];
    loadx8(xr3, xlane + 3 * F_IN, tail);  mr3 = mptr[3 * F_IN];

    // ---- pipeline prologue: accx for t=0 ----
    floatx4 accx_p[8];
    {
        HU xu;
        xu.u[0] = cvtpk(xr0[0], xr0[1]);
        xu.u[1] = cvtpk(xr0[2], xr0[3]);
        xu.u[2] = cvtpk(xr0[4], xr0[5]);
        xu.u[3] = tail ? 0x3f803f80u : cvtpk(xr0[6], xr0[7]);
#pragma unroll
        for (int mt = 0; mt < 8; ++mt) {
            floatx4 a = {0.f, 0.f, 0.f, 0.f};
            a = MFMA(wxh[mt], xu.s, a);
            a = MFMA(wxl[mt], xu.s, a);
            accx_p[mt] = a;
        }
    }
    HU Oh, Ol;    // masked out-tile of previous step (head operand), lagged
#pragma unroll
    for (int w = 0; w < 4; ++w) { Oh.u[w] = 0u; Ol.u[w] = 0u; }

    auto step = [&](int t, float (&xr_cur)[8], float& mr_cur, float (&xr_nxt)[8]) {
        const float mcur = mr_cur;
        // 1. recurrent h-MFMAs, seeded with accx_p as C-in (order: x-hi,x-lo,h-hh,h-hl,h-lh
        //    == round-4 accumulation order, numerics identical)
        const short8 hah = Hh.s, hal = Hl.s;
        floatx4 acc[8];
#pragma unroll
        for (int mt = 0; mt < 8; ++mt) {
            floatx4 a = accx_p[mt];
            a = MFMA(whh[mt], hah, a);
            a = MFMA(whh[mt], hal, a);
            a = MFMA(whl[mt], hah, a);
            acc[mt] = a;
        }
        // 2. next-step x partials (independent filler for the h-chain latency)
        HU xu;
        xu.u[0] = cvtpk(xr_nxt[0], xr_nxt[1]);
        xu.u[1] = cvtpk(xr_nxt[2], xr_nxt[3]);
        xu.u[2] = cvtpk(xr_nxt[4], xr_nxt[5]);
        xu.u[3] = tail ? 0x3f803f80u : cvtpk(xr_nxt[6], xr_nxt[7]);
        floatx4 accx_n[8];
#pragma unroll
        for (int mt = 0; mt < 8; ++mt) {
            floatx4 a = {0.f, 0.f, 0.f, 0.f};
            a = MFMA(wxh[mt], xu.s, a);
            a = MFMA(wxl[mt], xu.s, a);
            accx_n[mt] = a;
        }
        // 3. head for step t-1 (filler; operands from last step's pack)
        if (t != 0) {
            floatx4 ha = {0.f, 0.f, 0.f, 0.f};
            ha = MFMA(wph, Oh.s, ha);
            ha = MFMA(wph, Ol.s, ha);
            ha = MFMA(wpl, Oh.s, ha);
            if (quad == 0) {
                const size_t o = (size_t)row * T_STEPS + (t - 1);
                *(float2*)&pos_out[o * 2] = make_float2(ha[0] + bc0, ha[1] + bc1);
                const float z = ha[2] + blv;
                lv_out[o] = rcp_f(1.0f + exp2_f(-LOG2E * z));
            }
        }
        // 4. prefetch t+4 into the current ring slot
        {
            const int tp = (t + 4 < T_STEPS) ? t + 4 : (T_STEPS - 1);
            loadx8(xr_cur, xlane + (size_t)tp * F_IN, tail);
            mr_cur = mptr[(size_t)tp * F_IN];
        }
        // 5. activations (exp2-folded, no fp32 division)
        float act[8][4];
#pragma unroll
        for (int mt = 0; mt < 8; ++mt) {
            const bool isg = (mt == 4) || (mt == 5);
#pragma unroll
            for (int r = 0; r < 4; ++r) {
                const float rr = rcp_f(1.0f + exp2_f(acc[mt][r]));
                act[mt][r] = isg ? fmaf(2.0f, rr, -1.0f) : rr;
            }
        }
        // 6. lane-local state update: unit j (phys 8*quad+j)
        const bool on = (mcur == 1.0f);
        float hn[8];
#pragma unroll
        for (int j = 0; j < 8; ++j) {
            const int tI = j >> 2, r = j & 3;
            const float gi = act[0 + tI][r], gf = act[2 + tI][r];
            const float gg = act[4 + tI][r], go = act[6 + tI][r];
            const float cn = gf * cst[j] + gi * gg;
            const float tn = fmaf(2.0f, rcp_f(1.0f + exp2_f(-2.0f * LOG2E * cn)), -1.0f);
            hn[j] = go * tn;
            cst[j] = on ? cn : cst[j];
        }
        // 7. pack h_new -> bf16 hi/lo; commit state + lagged head operand
#pragma unroll
        for (int w = 0; w < 4; ++w) {
            const uint32_t ph = cvtpk(hn[2 * w], hn[2 * w + 1]);
            const float r0 = hn[2 * w]     - __uint_as_float(ph << 16);
            const float r1 = hn[2 * w + 1] - __uint_as_float(ph & 0xffff0000u);
            const uint32_t pl = cvtpk(r0, r1);
            Oh.u[w] = on ? ph : 0u;
            Ol.u[w] = on ? pl : 0u;
            Hh.u[w] = on ? ph : Hh.u[w];
            Hl.u[w] = on ? pl : Hl.u[w];
        }
        // 8. rotate the x-partial pipeline register
#pragma unroll
        for (int mt = 0; mt < 8; ++mt) accx_p[mt] = accx_n[mt];
    };

#pragma unroll 1
    for (int t = 0; t < T_STEPS; t += 4) {
        step(t + 0, xr0, mr0, xr1);
        step(t + 1, xr1, mr1, xr2);
        step(t + 2, xr2, mr2, xr3);
        step(t + 3, xr3, mr3, xr0);
    }

    // epilogue: head for the final step (t = T_STEPS-1)
    {
        floatx4 ha = {0.f, 0.f, 0.f, 0.f};
        ha = MFMA(wph, Oh.s, ha);
        ha = MFMA(wph, Ol.s, ha);
        ha = MFMA(wpl, Oh.s, ha);
        if (quad == 0) {
            const size_t o = (size_t)row * T_STEPS + (T_STEPS - 1);
            *(float2*)&pos_out[o * 2] = make_float2(ha[0] + bc0, ha[1] + bc1);
            const float z = ha[2] + blv;
            lv_out[o] = rcp_f(1.0f + exp2_f(-LOG2E * z));
        }
    }

    // final state: reconstruct fp32 h from hi+lo (error ~2^-18, well under tolerance)
    {
        float* hp = hT_out + (size_t)row * HID + quad * 8;
        float* cp = cT_out + (size_t)row * HID + quad * 8;
#pragma unroll
        for (int w = 0; w < 4; ++w) {
            hp[2 * w]     = __uint_as_float(Hh.u[w] << 16)        + __uint_as_float(Hl.u[w] << 16);
            hp[2 * w + 1] = __uint_as_float(Hh.u[w] & 0xffff0000u) + __uint_as_float(Hl.u[w] & 0xffff0000u);
        }
#pragma unroll
        for (int j = 0; j < 8; ++j) cp[j] = cst[j];
    }
}

extern "C" void kernel_launch(void* const* d_in, const int* in_sizes, int n_in,
                              void* d_out, int out_size, void* d_ws, size_t ws_size,
                              hipStream_t stream) {
    const float* x     = (const float*)d_in[0];
    const float* h0    = (const float*)d_in[1];
    const float* c0    = (const float*)d_in[2];
    const float* W_ih  = (const float*)d_in[3];
    const float* W_hh  = (const float*)d_in[4];
    const float* b_ih  = (const float*)d_in[5];
    const float* b_hh  = (const float*)d_in[6];
    const float* W_all = (const float*)d_in[7];
    const float* b_all = (const float*)d_in[8];
    const float* W_pos = (const float*)d_in[9];
    const float* b_pos = (const float*)d_in[10];
    const float* W_lv  = (const float*)d_in[11];
    const float* b_lv  = (const float*)d_in[12];

    const int B = in_sizes[1] / HID;         // h0 is [1,B,H] -> 4096
    float* out     = (float*)d_out;
    float* pos_out = out;                                    // [B,T,2]
    float* lv_out  = pos_out + (size_t)B * T_STEPS * 2;      // [B,T,1]
    float* hT_out  = lv_out  + (size_t)B * T_STEPS;          // [1,B,H]
    float* cT_out  = hT_out  + (size_t)B * HID;              // [1,B,H]

    dim3 grid(B / 16), block(64);
    hipLaunchKernelGGL(lstm_wave_kernel, grid, block, 0, stream,
                       x, h0, c0, W_ih, W_hh, b_ih, b_hh, W_all, b_all,
                       W_pos, b_pos, W_lv, b_lv, pos_out, lv_out, hT_out, cT_out);
}

// Round 6
// 638.590 us; speedup vs baseline: 1.2355x; 1.2355x over previous
//
#include <hip/hip_runtime.h>
#include <stdint.h>

#define T_STEPS 512
#define F_IN 30
#define HID 32
#define LOG2E 1.44269504088896340736f

typedef __attribute__((ext_vector_type(8))) short short8;   // 8 bf16 (4 VGPRs)
typedef __attribute__((ext_vector_type(4))) float floatx4;  // 4 f32 acc

#define MFMA(a, b, c) __builtin_amdgcn_mfma_f32_16x16x32_bf16((a), (b), (c), 0, 0, 0)

// Raw barrier: drain LDS only (lgkmcnt); thread-private global prefetches ride across.
#define BAR() asm volatile("s_waitcnt lgkmcnt(0)\n\ts_barrier" ::: "memory")

__device__ __forceinline__ unsigned short f2bf(float f) {
    uint32_t u = __float_as_uint(f);
    u += 0x7fffu + ((u >> 16) & 1u);            // RTNE
    return (unsigned short)(u >> 16);
}
__device__ __forceinline__ float bf2f(unsigned short h) {
    return __uint_as_float(((uint32_t)h) << 16);
}
// packed f32->bf16 RTNE, single VALU op (gfx950); lo16 = S0, hi16 = S1
__device__ __forceinline__ uint32_t cvtpk(float a, float b) {
    uint32_t r;
    asm("v_cvt_pk_bf16_f32 %0, %1, %2" : "=v"(r) : "v"(a), "v"(b));
    return r;
}
__device__ __forceinline__ float rcp_f(float x) { return __builtin_amdgcn_rcpf(x); }
#if __has_builtin(__builtin_amdgcn_exp2f)
__device__ __forceinline__ float exp2_f(float x) { return __builtin_amdgcn_exp2f(x); }
#else
__device__ __forceinline__ float exp2_f(float x) { return exp2f(x); }
#endif

__device__ __forceinline__ void loadx8(float (&d)[8], const float* p, bool tail) {
    float2 a0 = *(const float2*)(p + 0);
    float2 a1 = *(const float2*)(p + 2);
    float2 a2 = *(const float2*)(p + 4);
    float2 a3 = make_float2(0.f, 0.f);
    if (!tail) a3 = *(const float2*)(p + 6);     // quad3: feats 24..29; slots 6,7 set at cvt
    d[0]=a0.x; d[1]=a0.y; d[2]=a1.x; d[3]=a1.y;
    d[4]=a2.x; d[5]=a2.y; d[6]=a3.x; d[7]=a3.y;
}

// Block = 256 threads = 4 waves = ONE 16-row LSTM chain; wave w owns gate type w
// (i,f,g,o). Each wave: 2 M-tiles (10 MFMAs), 8 activations/lane (16 trans vs 64
// in the single-wave kernel). Exchange act values + h(bf16 hi/lo) via small LDS
// with two lgkm-only barriers/step. Unit permutation P keeps the h exchange at
// one packed b32 write / b128 read per array. Grid = 256 blocks -> 1024 waves
// on 1024 SIMDs (vs 256 busy SIMDs before).
__global__ __launch_bounds__(256, 1)
void lstm_quad_kernel(const float* __restrict__ x, const float* __restrict__ h0,
                      const float* __restrict__ c0, const float* __restrict__ W_ih,
                      const float* __restrict__ W_hh, const float* __restrict__ b_ih,
                      const float* __restrict__ b_hh, const float* __restrict__ W_all,
                      const float* __restrict__ b_all, const float* __restrict__ W_pos,
                      const float* __restrict__ b_pos, const float* __restrict__ W_lv,
                      const float* __restrict__ b_lv, float* __restrict__ pos_out,
                      float* __restrict__ lv_out, float* __restrict__ hT_out,
                      float* __restrict__ cT_out)
{
    const int tid  = threadIdx.x;
    const int wv   = tid >> 6;        // wave = gate type: 0=i, 1=f, 2=g, 3=o
    const int lane = tid & 63;
    const int quad = lane >> 4;
    const int l15  = lane & 15;
    const int row  = blockIdx.x * 16 + l15;

    __shared__ float gbuf[16][132];                          // [batch row][gate m], +4 pad
    __shared__ __align__(16) unsigned short hbh[16][40];     // h bf16 hi
    __shared__ __align__(16) unsigned short hbl[16][40];     // h bf16 lo
    __shared__ __align__(16) unsigned short obh[16][40];     // masked out hi (head operand)
    __shared__ __align__(16) unsigned short obl[16][40];     // masked out lo

    // ---- gate weight A-frags: this wave's two subtiles (global tiles 2wv, 2wv+1) ----
    // exp2-folded; k-slot 30 of the x-weights carries the bias (x slot 30 = 1.0).
    const bool  isg = (wv == 2);
    const float gs  = (isg ? -2.0f : -1.0f) * LOG2E;
    short8 wxh[2], wxl[2], whh[2], whl[2];
#pragma unroll
    for (int s = 0; s < 2; ++s) {
        const int m = (2 * wv + s) * 16 + l15;
        const int c = m & 31;
        const int u = 8 * ((c & 15) >> 2) + 4 * (c >> 4) + (c & 3);   // P(c)
        const int R = (m >> 5) * 32 + u;                              // original weight row
        const float bias = (b_ih[R] + b_hh[R]) * gs;
#pragma unroll
        for (int j = 0; j < 8; ++j) {
            const int k = quad * 8 + j;
            float wx = (k < F_IN) ? W_ih[R * F_IN + k] * gs : (k == F_IN ? bias : 0.0f);
            unsigned short hx = f2bf(wx);
            wxh[s][j] = (short)hx; wxl[s][j] = (short)f2bf(wx - bf2f(hx));
            float wh = W_hh[R * HID + k] * gs;
            unsigned short hh = f2bf(wh);
            whh[s][j] = (short)hh; whl[s][j] = (short)f2bf(wh - bf2f(hh));
        }
    }

    // ---- head A-frags (used by wave 3): m-row 0 = pos0, 1 = pos1, 2 = leave ----
    short8 wph, wpl;
#pragma unroll
    for (int j = 0; j < 8; ++j) {
        const int k = quad * 8 + j;   // physical hidden unit
        float w = 0.0f;
        if (l15 == 0)      { for (int o = 0; o < HID; ++o) w += W_pos[o]       * W_all[o * HID + k]; }
        else if (l15 == 1) { for (int o = 0; o < HID; ++o) w += W_pos[HID + o] * W_all[o * HID + k]; }
        else if (l15 == 2) { w = W_lv[k]; }
        unsigned short hw_ = f2bf(w);
        wph[j] = (short)hw_; wpl[j] = (short)f2bf(w - bf2f(hw_));
    }
    float bc0 = b_pos[0], bc1 = b_pos[1];
    for (int o = 0; o < HID; ++o) { bc0 += W_pos[o] * b_all[o]; bc1 += W_pos[HID + o] * b_all[o]; }
    const float blv = b_lv[0];

    // ---- update role: this lane owns (row, units u0, u0+1), u0 = 8*quad + 2*wv ----
    const int u0 = 8 * quad + 2 * wv;
    float c_st0, c_st1, h_st0, h_st1;
    {
        const float2 cc = *(const float2*)&c0[(size_t)row * HID + u0];
        const float2 hh2 = *(const float2*)&h0[(size_t)row * HID + u0];
        c_st0 = cc.x; c_st1 = cc.y; h_st0 = hh2.x; h_st1 = hh2.y;
        const uint32_t ph = cvtpk(h_st0, h_st1);
        const float r0 = h_st0 - __uint_as_float(ph << 16);
        const float r1 = h_st1 - __uint_as_float(ph & 0xffff0000u);
        *(uint32_t*)&hbh[l15][u0] = ph;
        *(uint32_t*)&hbl[l15][u0] = cvtpk(r0, r1);
        *(uint32_t*)&obh[l15][u0] = 0u;
        *(uint32_t*)&obl[l15][u0] = 0u;
    }

    // ---- x / mask prefetch ring (depth 4); every wave loads the same x (L1/L2 hit) ----
    const float* xlane = x + (size_t)row * T_STEPS * F_IN + quad * 8;
    const float* mptr  = x + (size_t)row * T_STEPS * F_IN + (F_IN - 1);
    const bool tail = (quad == 3);

    float xr0[8], xr1[8], xr2[8], xr3[8];
    float mr0, mr1, mr2, mr3;
    loadx8(xr0, xlane + 0 * F_IN, tail);  mr0 = mptr[0 * F_IN];
    loadx8(xr1, xlane + 1 * F_IN, tail);  mr1 = mptr[1 * F_IN];
    loadx8(xr2, xlane + 2 * F_IN, tail);  mr2 = mptr[2 * F_IN];
    loadx8(xr3, xlane + 3 * F_IN, tail);  mr3 = mptr[3 * F_IN];

    BAR();   // h/ob init visible

    union HU { uint32_t u[4]; short8 s; };

    auto step = [&](int t, float (&xr)[8], float& mr) {
        const float mcur = mr;
        // h B-frag (all units, written by all 4 waves last step; visible after BAR B)
        const short8 hah = *(const short8*)&hbh[l15][quad * 8];
        const short8 hal = *(const short8*)&hbl[l15][quad * 8];
        // wave3: head operands for step t-1
        short8 oah, oal;
        if (wv == 3 && t > 0) {
            oah = *(const short8*)&obh[l15][quad * 8];
            oal = *(const short8*)&obl[l15][quad * 8];
        }
        // x B-frag (slot 30/31 = 1.0 -> bias via weight slot 30)
        HU xu;
        xu.u[0] = cvtpk(xr[0], xr[1]);
        xu.u[1] = cvtpk(xr[2], xr[3]);
        xu.u[2] = cvtpk(xr[4], xr[5]);
        xu.u[3] = tail ? 0x3f803f80u : cvtpk(xr[6], xr[7]);
        // prefetch t+4 into this ring slot (rides across barriers)
        {
            const int tp = (t + 4 < T_STEPS) ? t + 4 : (T_STEPS - 1);
            loadx8(xr, xlane + (size_t)tp * F_IN, tail);
            mr = mptr[(size_t)tp * F_IN];
        }
        // 2 subtiles x 5 MFMAs, same per-acc order as the verified kernel
        floatx4 a0 = {0.f, 0.f, 0.f, 0.f}, a1 = {0.f, 0.f, 0.f, 0.f};
        a0 = MFMA(wxh[0], xu.s, a0);  a1 = MFMA(wxh[1], xu.s, a1);
        a0 = MFMA(wxl[0], xu.s, a0);  a1 = MFMA(wxl[1], xu.s, a1);
        a0 = MFMA(whh[0], hah, a0);   a1 = MFMA(whh[1], hah, a1);
        a0 = MFMA(whh[0], hal, a0);   a1 = MFMA(whh[1], hal, a1);
        a0 = MFMA(whl[0], hah, a0);   a1 = MFMA(whl[1], hah, a1);
        // wave3: heads for step t-1 (independent filler; global stores only)
        if (wv == 3 && t > 0) {
            floatx4 ha = {0.f, 0.f, 0.f, 0.f};
            ha = MFMA(wph, oah, ha);
            ha = MFMA(wph, oal, ha);
            ha = MFMA(wpl, oah, ha);
            if (quad == 0) {
                const size_t o = (size_t)row * T_STEPS + (t - 1);
                *(float2*)&pos_out[o * 2] = make_float2(ha[0] + bc0, ha[1] + bc1);
                lv_out[o] = rcp_f(1.0f + exp2_f(-LOG2E * (ha[2] + blv)));
            }
        }
        // activations: 8 values/lane (16 trans vs 64 single-wave)
        float4 v0, v1;
        {
            const float q00 = rcp_f(1.0f + exp2_f(a0[0])), q01 = rcp_f(1.0f + exp2_f(a0[1]));
            const float q02 = rcp_f(1.0f + exp2_f(a0[2])), q03 = rcp_f(1.0f + exp2_f(a0[3]));
            const float q10 = rcp_f(1.0f + exp2_f(a1[0])), q11 = rcp_f(1.0f + exp2_f(a1[1]));
            const float q12 = rcp_f(1.0f + exp2_f(a1[2])), q13 = rcp_f(1.0f + exp2_f(a1[3]));
            if (isg) {
                v0 = make_float4(fmaf(2.f,q00,-1.f), fmaf(2.f,q01,-1.f), fmaf(2.f,q02,-1.f), fmaf(2.f,q03,-1.f));
                v1 = make_float4(fmaf(2.f,q10,-1.f), fmaf(2.f,q11,-1.f), fmaf(2.f,q12,-1.f), fmaf(2.f,q13,-1.f));
            } else {
                v0 = make_float4(q00, q01, q02, q03);
                v1 = make_float4(q10, q11, q12, q13);
            }
        }
        // scatter to gate buffer: value (s,r) -> column 32*wv + 16*s + 4*quad + r
        *(float4*)&gbuf[l15][32 * wv + 4 * quad]      = v0;
        *(float4*)&gbuf[l15][32 * wv + 16 + 4 * quad] = v1;
        BAR();   // A: gates visible
        // gate gather for units u0, u0+1 (consecutive columns by P-algebra)
        const int goff = 16 * (wv >> 1) + 4 * quad + 2 * (wv & 1);
        const float2 gi = *(const float2*)&gbuf[l15][goff];
        const float2 gf = *(const float2*)&gbuf[l15][32 + goff];
        const float2 gg = *(const float2*)&gbuf[l15][64 + goff];
        const float2 go = *(const float2*)&gbuf[l15][96 + goff];
        const bool on = (mcur == 1.0f);
        const float cn0 = gf.x * c_st0 + gi.x * gg.x;
        const float tn0 = fmaf(2.0f, rcp_f(1.0f + exp2_f(-2.0f * LOG2E * cn0)), -1.0f);
        const float hn0 = go.x * tn0;
        const float cn1 = gf.y * c_st1 + gi.y * gg.y;
        const float tn1 = fmaf(2.0f, rcp_f(1.0f + exp2_f(-2.0f * LOG2E * cn1)), -1.0f);
        const float hn1 = go.y * tn1;
        if (on) { c_st0 = cn0; c_st1 = cn1; h_st0 = hn0; h_st1 = hn1; }
        // pack 2 units -> one b32 each for hi/lo; cvtpk output IS the packed pair
        const uint32_t ph = cvtpk(hn0, hn1);
        const float r0 = hn0 - __uint_as_float(ph << 16);
        const float r1 = hn1 - __uint_as_float(ph & 0xffff0000u);
        const uint32_t pl = cvtpk(r0, r1);
        *(uint32_t*)&obh[l15][u0] = on ? ph : 0u;
        *(uint32_t*)&obl[l15][u0] = on ? pl : 0u;
        if (on) {
            *(uint32_t*)&hbh[l15][u0] = ph;
            *(uint32_t*)&hbl[l15][u0] = pl;
        }
        BAR();   // B: h/ob visible for next step
    };

#pragma unroll 1
    for (int t = 0; t < T_STEPS; t += 4) {
        step(t + 0, xr0, mr0);
        step(t + 1, xr1, mr1);
        step(t + 2, xr2, mr2);
        step(t + 3, xr3, mr3);
    }

    // epilogue: head for t = T_STEPS-1 (ob written before final BAR B)
    if (wv == 3) {
        const short8 oah = *(const short8*)&obh[l15][quad * 8];
        const short8 oal = *(const short8*)&obl[l15][quad * 8];
        floatx4 ha = {0.f, 0.f, 0.f, 0.f};
        ha = MFMA(wph, oah, ha);
        ha = MFMA(wph, oal, ha);
        ha = MFMA(wpl, oah, ha);
        if (quad == 0) {
            const size_t o = (size_t)row * T_STEPS + (T_STEPS - 1);
            *(float2*)&pos_out[o * 2] = make_float2(ha[0] + bc0, ha[1] + bc1);
            lv_out[o] = rcp_f(1.0f + exp2_f(-LOG2E * (ha[2] + blv)));
        }
    }

    // final state: lane owns units u0, u0+1 of its row (exact fp32 states)
    *(float2*)&hT_out[(size_t)row * HID + u0] = make_float2(h_st0, h_st1);
    *(float2*)&cT_out[(size_t)row * HID + u0] = make_float2(c_st0, c_st1);
}

extern "C" void kernel_launch(void* const* d_in, const int* in_sizes, int n_in,
                              void* d_out, int out_size, void* d_ws, size_t ws_size,
                              hipStream_t stream) {
    const float* x     = (const float*)d_in[0];
    const float* h0    = (const float*)d_in[1];
    const float* c0    = (const float*)d_in[2];
    const float* W_ih  = (const float*)d_in[3];
    const float* W_hh  = (const float*)d_in[4];
    const float* b_ih  = (const float*)d_in[5];
    const float* b_hh  = (const float*)d_in[6];
    const float* W_all = (const float*)d_in[7];
    const float* b_all = (const float*)d_in[8];
    const float* W_pos = (const float*)d_in[9];
    const float* b_pos = (const float*)d_in[10];
    const float* W_lv  = (const float*)d_in[11];
    const float* b_lv  = (const float*)d_in[12];

    const int B = in_sizes[1] / HID;         // h0 is [1,B,H] -> 4096
    float* out     = (float*)d_out;
    float* pos_out = out;                                    // [B,T,2]
    float* lv_out  = pos_out + (size_t)B * T_STEPS * 2;      // [B,T,1]
    float* hT_out  = lv_out  + (size_t)B * T_STEPS;          // [1,B,H]
    float* cT_out  = hT_out  + (size_t)B * HID;              // [1,B,H]

    dim3 grid(B / 16), block(256);
    hipLaunchKernelGGL(lstm_quad_kernel, grid, block, 0, stream,
                       x, h0, c0, W_ih, W_hh, b_ih, b_hh, W_all, b_all,
                       W_pos, b_pos, W_lv, b_lv, pos_out, lv_out, hT_out, cT_out);
}